// Round 9
// baseline (216.186 us; speedup 1.0000x reference)
//
#include <hip/hip_runtime.h>
#include <math.h>

#define NO 10
#define NFEAT 68
#define HR 5
#define MAXNR 2048
#define MAXLIST 1024
#define MAXP 16384

// fent[oi*10+oj] = feature index | 256 (if fac==0.5), or -1 if below block-diagonal.
__device__ const int g_fent[100] = {
    256,  1,  2,  3,  4,  5,  6,  7,  8,  9,
     -1,266, 11, 12, 13, 14, 15, 16, 17, 18,
     -1, -1,275,276,277, 28, 29, 30, 31, 32,
     -1, -1,278,279,280, 33, 34, 35, 36, 37,
     -1, -1,281,282,283, 38, 39, 40, 41, 42,
     -1, -1, -1, -1, -1,299,300,301,302,303,
     -1, -1, -1, -1, -1,304,305,306,307,308,
     -1, -1, -1, -1, -1,309,310,311,312,313,
     -1, -1, -1, -1, -1,314,315,316,317,318,
     -1, -1, -1, -1, -1,319,320,321,322,323
};

// Packed feature table for the fallback kernel: bits0-3=oi, 4-7=oj, bit8=(fac==0.5)
__device__ const unsigned short g_pk[NFEAT] = {
    0x100, 0x010, 0x020, 0x030, 0x040, 0x050, 0x060, 0x070, 0x080, 0x090,
    0x111, 0x021, 0x031, 0x041, 0x051, 0x061, 0x071, 0x081, 0x091,
    0x122, 0x132, 0x142, 0x123, 0x133, 0x143, 0x124, 0x134, 0x144,
    0x052, 0x062, 0x072, 0x082, 0x092,
    0x053, 0x063, 0x073, 0x083, 0x093,
    0x054, 0x064, 0x074, 0x084, 0x094,
    0x155, 0x165, 0x175, 0x185, 0x195,
    0x156, 0x166, 0x176, 0x186, 0x196,
    0x157, 0x167, 0x177, 0x187, 0x197,
    0x158, 0x168, 0x178, 0x188, 0x198,
    0x159, 0x169, 0x179, 0x189, 0x199
};

// ---------- precompute (all parallel, <1MB ws) ----------

// g0: map=-1, paircnt=0, header=0, sin table.
__global__ void g0_init(const float* __restrict__ ecs, const float* __restrict__ kp,
                        float* __restrict__ sins, int* __restrict__ map,
                        int* __restrict__ paircnt, int* __restrict__ hdr,
                        int E, int N, int NK) {
    int idx = blockIdx.x * blockDim.x + threadIdx.x;
    int stride = gridDim.x * blockDim.x;
    const float TWO_PI = 6.283185307179586f;
    for (int x = idx; x < NK * E; x += stride) {
        int k = x / E, e = x - k * E;
        float th = TWO_PI * (kp[k*3]*ecs[e*3] + kp[k*3+1]*ecs[e*3+1] + kp[k*3+2]*ecs[e*3+2]);
        sins[x] = sinf(th);
    }
    for (int x = idx; x < N * N; x += stride) map[x] = -1;
    for (int x = idx; x < MAXP; x += stride) paircnt[x] = 0;
    if (idx == 0) { hdr[0] = 0; hdr[1] = 0; }
}

// g1: claim one pair id per distinct ordered (a,b) with an edge orientation.
__global__ void g1_claim(const int* __restrict__ eidx, int* __restrict__ map,
                         int* __restrict__ hdr, int E, int N) {
    int idx = blockIdx.x * blockDim.x + threadIdx.x;
    if (idx >= 2 * E) return;
    int o = idx >= E;
    int e = o ? idx - E : idx;
    int src = eidx[e], dst = eidx[E + e];
    int a = o ? dst : src, b = o ? src : dst;
    int old = atomicCAS(&map[a * N + b], -1, -2);
    if (old == -1) {
        int pid = atomicAdd(&hdr[0], 1);
        map[a * N + b] = (pid < MAXP) ? pid : -1;
    }
}

// g2: count entries per pair.
__global__ void g2_count(const int* __restrict__ eidx, const int* __restrict__ map,
                         int* __restrict__ paircnt, int E, int N) {
    int idx = blockIdx.x * blockDim.x + threadIdx.x;
    if (idx >= 2 * E) return;
    int o = idx >= E;
    int e = o ? idx - E : idx;
    int src = eidx[e], dst = eidx[E + e];
    int a = o ? dst : src, b = o ? src : dst;
    int pid = map[a * N + b];
    if (pid >= 0) atomicAdd(&paircnt[pid], 1);
}

// g3: CSR offsets via atomic allocation (order-free), parallel over all MAXP slots.
__global__ void g3_off(const int* __restrict__ paircnt, int* __restrict__ pairoff,
                       int* __restrict__ paircur, int* __restrict__ hdr) {
    int pid = blockIdx.x * blockDim.x + threadIdx.x;
    if (pid >= MAXP) return;
    int cnt = paircnt[pid];
    int off = cnt ? atomicAdd(&hdr[1], cnt) : 0;
    pairoff[pid] = off;
    paircur[pid] = off;
}

// g4: fill CSR entries (entry = e*2 + orientation).
__global__ void g4_fill(const int* __restrict__ eidx, const int* __restrict__ map,
                        int* __restrict__ paircur, int* __restrict__ entries,
                        int E, int N) {
    int idx = blockIdx.x * blockDim.x + threadIdx.x;
    if (idx >= 2 * E) return;
    int o = idx >= E;
    int e = o ? idx - E : idx;
    int src = eidx[e], dst = eidx[E + e];
    int a = o ? dst : src, b = o ? src : dst;
    int pid = map[a * N + b];
    if (pid >= 0) {
        int pos = atomicAdd(&paircur[pid], 1);
        if (pos < 2 * E) entries[pos] = e * 2 + o;
    }
}

// main: pure grid-stride streaming store + conditional gather.
// out[((d*NK+k)*NR + r)*NR + c] = onsite(i==j) + sum_{edges of block (i,j)} contribution.
__global__ __launch_bounds__(256)
void main_gather(const float* __restrict__ ef, const float* __restrict__ nf,
                 const float* __restrict__ ev, const int* __restrict__ eidx,
                 const float* __restrict__ sins, const int* __restrict__ map,
                 const int* __restrict__ pairoff, const int* __restrict__ paircnt,
                 const int* __restrict__ entries, float* __restrict__ out,
                 int E, int N, int NK, size_t n4) {
    __shared__ int sfent[100];
    if (threadIdx.x < 100) sfent[threadIdx.x] = g_fent[threadIdx.x];
    __syncthreads();
    const int NR = N * NO;
    const int perk = NR * NR;
    size_t stride = (size_t)gridDim.x * blockDim.x;
    for (size_t q = (size_t)blockIdx.x * blockDim.x + threadIdx.x; q < n4; q += stride) {
        int F = (int)(q * 4);
        int dk = F / perk;
        int rem = F - dk * perk;
        int r = rem / NR;
        int c0 = rem - r * NR;
        int k = dk % NK;            // layout index = d*NK + k
        int d = dk / NK;
        int i = r / NO;
        int ri = r - i * NO;
        const int* mrow = map + i * N;
        const float* sk = sins + k * E;
        float v[4];
#pragma unroll
        for (int t = 0; t < 4; ++t) {
            int c = c0 + t;
            int j = c / NO;
            int cj = c - j * NO;
            float s = 0.f;
            if (i == j) {
                int fe = sfent[ri * NO + cj];
                if (fe >= 0) s += ((fe & 256) ? 0.5f : 1.f) * nf[i * NFEAT + (fe & 255)];
                int ft = sfent[cj * NO + ri];
                if (ft >= 0) s += ((ft & 256) ? 0.5f : 1.f) * nf[i * NFEAT + (ft & 255)];
            }
            int pid = mrow[j];
            if (pid >= 0) {
                int off = pairoff[pid], cnt = paircnt[pid];
                for (int x = 0; x < cnt; ++x) {
                    int ent = entries[off + x];
                    int e = ent >> 1, o = ent & 1;
                    int fe = o ? sfent[cj * NO + ri] : sfent[ri * NO + cj];
                    if (fe >= 0)
                        s += ((fe & 256) ? 0.5f : 1.f) * ef[e * NFEAT + (fe & 255)]
                           * (-ev[e * 3 + d]) * sk[e];
                }
            }
            v[t] = s;
        }
        *(float4*)(out + q * 4) = make_float4(v[0], v[1], v[2], v[3]);
    }
}

// ---------- fallback (round-7 kernel, 95 us) ----------
__global__ __launch_bounds__(512)
void fused1d(const float* __restrict__ ef, const float* __restrict__ nf,
             const float* __restrict__ ev, const float* __restrict__ ecs,
             const float* __restrict__ kp, const int* __restrict__ eidx,
             float* __restrict__ out,
             int E, int N, int NK, size_t lim) {
    __shared__ float acc[HR * MAXNR];
    __shared__ float coef[MAXLIST];
    __shared__ int   elist[MAXLIST];
    __shared__ int   mcnt;
    const int i = blockIdx.x, k = blockIdx.y;
    const int d = blockIdx.z >> 1, h = blockIdx.z & 1;
    const int r0 = h * HR;
    const int tid = threadIdx.x, nthr = blockDim.x;
    const int NR = N * NO;
    if (NR > MAXNR) return;
    if (tid == 0) mcnt = 0;
    __syncthreads();
    for (int e = tid; e < E; e += nthr) {
        int s = eidx[e], t = eidx[E + e];
        if (s == i) { int p = atomicAdd(&mcnt, 1); if (p < MAXLIST) elist[p] = e * 2; }
        if (t == i) { int p = atomicAdd(&mcnt, 1); if (p < MAXLIST) elist[p] = e * 2 + 1; }
    }
    {
        float4* a4 = (float4*)acc;
        int nz = (HR * NR) >> 2;
        float4 z = make_float4(0.f, 0.f, 0.f, 0.f);
        for (int x = tid; x < nz; x += nthr) a4[x] = z;
    }
    __syncthreads();
    const int m = min(mcnt, MAXLIST);
    const float k0v = kp[k*3], k1v = kp[k*3+1], k2v = kp[k*3+2];
    const float TWO_PI = 6.283185307179586f;
    for (int t = tid; t < m; t += nthr) {
        int e = elist[t] >> 1;
        float th = TWO_PI * (k0v*ecs[e*3] + k1v*ecs[e*3+1] + k2v*ecs[e*3+2]);
        coef[t] = -ev[e*3 + d] * sinf(th);
    }
    __syncthreads();
    const int items = m * NFEAT;
    for (int it = tid; it < items; it += nthr) {
        int t = it / NFEAT, f = it - t * NFEAT;
        int ent = elist[t], e = ent >> 1, dir = ent & 1;
        unsigned pk = g_pk[f];
        int oi = pk & 15, oj = (pk >> 4) & 15;
        int row = dir ? oj : oi, rr = row - r0;
        if ((unsigned)rr < HR) {
            int col = dir ? oi : oj;
            int j = dir ? eidx[e] : eidx[E + e];
            float fac = (pk & 256) ? 0.5f : 1.0f;
            atomicAdd(&acc[rr * NR + j * NO + col], coef[t] * fac * ef[e * NFEAT + f]);
        }
    }
    for (int f = tid; f < NFEAT; f += nthr) {
        unsigned pk = g_pk[f];
        int oi = pk & 15, oj = (pk >> 4) & 15;
        float v = ((pk & 256) ? 0.5f : 1.0f) * nf[i * NFEAT + f];
        int ra = oi - r0, rb = oj - r0;
        if ((unsigned)ra < HR) atomicAdd(&acc[ra * NR + i * NO + oj], v);
        if ((unsigned)rb < HR) atomicAdd(&acc[rb * NR + i * NO + oi], v);
    }
    __syncthreads();
    size_t base = ((size_t)(d * NK + k)) * NR * NR + (size_t)(i * NO + r0) * NR;
    int ntot = HR * NR;
    if ((NR & 3) == 0) {
        const float4* a4 = (const float4*)acc;
        int n4 = ntot >> 2;
        for (int x = tid; x < n4; x += nthr) {
            size_t idx = base + (size_t)x * 4;
            if (idx + 3 < lim) *(float4*)(out + idx) = a4[x];
        }
    } else {
        for (int x = tid; x < ntot; x += nthr) {
            size_t idx = base + x;
            if (idx < lim) out[idx] = acc[x];
        }
    }
}

extern "C" void kernel_launch(void* const* d_in, const int* in_sizes, int n_in,
                              void* d_out, int out_size, void* d_ws, size_t ws_size,
                              hipStream_t stream) {
    const float* ef  = (const float*)d_in[0];
    const float* nf  = (const float*)d_in[1];
    const float* ev  = (const float*)d_in[2];
    const float* ecs = (const float*)d_in[3];
    const float* kp  = (const float*)d_in[4];
    const int*  eidx = (const int*)d_in[5];
    float* out = (float*)d_out;

    int E  = in_sizes[0] / NFEAT;
    int N  = in_sizes[1] / NFEAT;
    int NK = in_sizes[4] / 3;
    int NR = N * NO;
    size_t lim = (size_t)out_size;   // 3*NK*NR*NR floats (real part)

    // workspace layout
    size_t o = 0;
    auto alloc = [&](size_t bytes) { size_t r = o; o = (o + bytes + 255) & ~(size_t)255; return r; };
    size_t o_hdr     = alloc(2 * 4);
    size_t o_sins    = alloc((size_t)NK * E * 4);
    size_t o_map     = alloc((size_t)N * N * 4);
    size_t o_paircnt = alloc((size_t)MAXP * 4);
    size_t o_pairoff = alloc((size_t)MAXP * 4);
    size_t o_paircur = alloc((size_t)MAXP * 4);
    size_t o_entries = alloc((size_t)2 * E * 4);
    size_t need = o;

    bool ok = (ws_size >= need) && ((NR & 3) == 0) && (NR <= MAXNR) &&
              ((size_t)2 * E <= (size_t)MAXP) && (lim == (size_t)3 * NK * NR * NR);

    if (!ok) {
        dim3 grid(N, NK, 6);
        fused1d<<<grid, 512, 0, stream>>>(ef, nf, ev, ecs, kp, eidx, out, E, N, NK, lim);
        return;
    }

    char* ws = (char*)d_ws;
    int*   hdr     = (int*)(ws + o_hdr);
    float* sins    = (float*)(ws + o_sins);
    int*   map     = (int*)(ws + o_map);
    int*   paircnt = (int*)(ws + o_paircnt);
    int*   pairoff = (int*)(ws + o_pairoff);
    int*   paircur = (int*)(ws + o_paircur);
    int*   entries = (int*)(ws + o_entries);

    int eb = (2 * E + 255) / 256;
    g0_init<<<256, 256, 0, stream>>>(ecs, kp, sins, map, paircnt, hdr, E, N, NK);
    g1_claim<<<eb, 256, 0, stream>>>(eidx, map, hdr, E, N);
    g2_count<<<eb, 256, 0, stream>>>(eidx, map, paircnt, E, N);
    g3_off<<<MAXP / 256, 256, 0, stream>>>(paircnt, pairoff, paircur, hdr);
    g4_fill<<<eb, 256, 0, stream>>>(eidx, map, paircur, entries, E, N);

    size_t n4 = lim >> 2;
    main_gather<<<4096, 256, 0, stream>>>(ef, nf, ev, eidx, sins, map, pairoff, paircnt,
                                          entries, out, E, N, NK, n4);
}

// Round 10
// 133.049 us; speedup vs baseline: 1.6249x; 1.6249x over previous
//
#include <hip/hip_runtime.h>
#include <math.h>

#define NO 10
#define NFEAT 68
#define HR 5
#define MAXNR 2048
#define MAXLIST 1024
#define MAXP 16384

// fent[oi*10+oj] = feature index | 256 (if fac==0.5), or -1 if below block-diagonal.
__device__ const int g_fent[100] = {
    256,  1,  2,  3,  4,  5,  6,  7,  8,  9,
     -1,266, 11, 12, 13, 14, 15, 16, 17, 18,
     -1, -1,275,276,277, 28, 29, 30, 31, 32,
     -1, -1,278,279,280, 33, 34, 35, 36, 37,
     -1, -1,281,282,283, 38, 39, 40, 41, 42,
     -1, -1, -1, -1, -1,299,300,301,302,303,
     -1, -1, -1, -1, -1,304,305,306,307,308,
     -1, -1, -1, -1, -1,309,310,311,312,313,
     -1, -1, -1, -1, -1,314,315,316,317,318,
     -1, -1, -1, -1, -1,319,320,321,322,323
};

// Packed feature table (fallback kernel): bits0-3=oi, 4-7=oj, bit8=(fac==0.5)
__device__ const unsigned short g_pk[NFEAT] = {
    0x100, 0x010, 0x020, 0x030, 0x040, 0x050, 0x060, 0x070, 0x080, 0x090,
    0x111, 0x021, 0x031, 0x041, 0x051, 0x061, 0x071, 0x081, 0x091,
    0x122, 0x132, 0x142, 0x123, 0x133, 0x143, 0x124, 0x134, 0x144,
    0x052, 0x062, 0x072, 0x082, 0x092,
    0x053, 0x063, 0x073, 0x083, 0x093,
    0x054, 0x064, 0x074, 0x084, 0x094,
    0x155, 0x165, 0x175, 0x185, 0x195,
    0x156, 0x166, 0x176, 0x186, 0x196,
    0x157, 0x167, 0x177, 0x187, 0x197,
    0x158, 0x168, 0x178, 0x188, 0x198,
    0x159, 0x169, 0x179, 0x189, 0x199
};

// (a,b) for work item idx: idx<E edge fwd; idx<2E edge transposed; else diagonal atom.
__device__ __forceinline__ void decode_ab(const int* __restrict__ eidx, int E, int idx,
                                          int& a, int& b) {
    if (idx < E)          { a = eidx[idx];        b = eidx[E + idx]; }
    else if (idx < 2 * E) { int e = idx - E; a = eidx[E + e]; b = eidx[e]; }
    else                  { a = idx - 2 * E; b = a; }
}

// g0: init map/paircnt/hdr; build coefE[dk*(E+1)+e] = -v_d*sin(2pi k.R_e), sentinel e=E -> 1.
__global__ void g0_init(const float* __restrict__ ecs, const float* __restrict__ kp,
                        const float* __restrict__ ev, float* __restrict__ coefE,
                        int* __restrict__ map, int* __restrict__ paircnt,
                        int* __restrict__ hdr, int E, int N, int NK) {
    int idx = blockIdx.x * blockDim.x + threadIdx.x;
    int stride = gridDim.x * blockDim.x;
    const float TWO_PI = 6.283185307179586f;
    int E1 = E + 1;
    int NDK = 3 * NK;
    for (int x = idx; x < NDK * E1; x += stride) {
        int dk = x / E1, e = x - dk * E1;
        float v;
        if (e == E) v = 1.0f;
        else {
            int d = dk / NK, k = dk - d * NK;
            float th = TWO_PI * (kp[k*3]*ecs[e*3] + kp[k*3+1]*ecs[e*3+1] + kp[k*3+2]*ecs[e*3+2]);
            v = -ev[e * 3 + d] * sinf(th);
        }
        coefE[x] = v;
    }
    for (int x = idx; x < N * N; x += stride) map[x] = -1;
    for (int x = idx; x < MAXP; x += stride) paircnt[x] = 0;
    if (idx == 0) { hdr[0] = 0; hdr[1] = 0; }
}

// g1: claim a pair id per distinct ordered (a,b).
__global__ void g1_claim(const int* __restrict__ eidx, int* __restrict__ map,
                         int* __restrict__ hdr, int E, int N, int total) {
    int idx = blockIdx.x * blockDim.x + threadIdx.x;
    if (idx >= total) return;
    int a, b; decode_ab(eidx, E, idx, a, b);
    int old = atomicCAS(&map[a * N + b], -1, -2);
    if (old == -1) {
        int pid = atomicAdd(&hdr[0], 1);
        map[a * N + b] = (pid < MAXP) ? pid : -1;
    }
}

// g2: count entries per pair.
__global__ void g2_count(const int* __restrict__ eidx, const int* __restrict__ map,
                         int* __restrict__ paircnt, int E, int N, int total) {
    int idx = blockIdx.x * blockDim.x + threadIdx.x;
    if (idx >= total) return;
    int a, b; decode_ab(eidx, E, idx, a, b);
    int pid = map[a * N + b];
    if (pid >= 0) atomicAdd(&paircnt[pid], 1);
}

// g3: CSR offsets (order-free atomic allocation).
__global__ void g3_off(const int* __restrict__ paircnt, int* __restrict__ pairoff,
                       int* __restrict__ paircur, int* __restrict__ hdr) {
    int pid = blockIdx.x * blockDim.x + threadIdx.x;
    if (pid >= MAXP) return;
    int cnt = paircnt[pid];
    int off = cnt ? atomicAdd(&hdr[1], cnt) : 0;
    pairoff[pid] = off;
    paircur[pid] = off;
}

// g4: fill entries. Edge: ent = e*2+o. Diagonal: ent = 2E + atom.
__global__ void g4_fill(const int* __restrict__ eidx, const int* __restrict__ map,
                        int* __restrict__ paircur, int* __restrict__ entries,
                        int E, int N, int total) {
    int idx = blockIdx.x * blockDim.x + threadIdx.x;
    if (idx >= total) return;
    int a, b; decode_ab(eidx, E, idx, a, b);
    int pid = map[a * N + b];
    if (pid >= 0) {
        int pos = atomicAdd(&paircur[pid], 1);
        int ent;
        if (idx < E)          ent = idx * 2;
        else if (idx < 2 * E) ent = (idx - E) * 2 + 1;
        else                  ent = 2 * E + (idx - 2 * E);
        if (pos < total) entries[pos] = ent;
    }
}

// A: build Entryval[pos][100]: pre-reduced fac*ef blocks (transposed for o=1),
// diagonal entries = D + D^T from nf.
__global__ void a_build(const float* __restrict__ ef, const float* __restrict__ nf,
                        const int* __restrict__ entries, float* __restrict__ entval,
                        int E, int total) {
    int idx = blockIdx.x * blockDim.x + threadIdx.x;
    if (idx >= total * 100) return;
    int pos = idx / 100, elem = idx - pos * 100;
    int ri = elem / 10, cj = elem - ri * 10;
    int ent = entries[pos];
    float v = 0.f;
    if (ent < 2 * E) {
        int e = ent >> 1, o = ent & 1;
        int fe = o ? g_fent[cj * 10 + ri] : g_fent[ri * 10 + cj];
        if (fe >= 0) v = ((fe & 256) ? 0.5f : 1.f) * ef[e * NFEAT + (fe & 255)];
    } else {
        int a = ent - 2 * E;
        int f1 = g_fent[ri * 10 + cj];
        if (f1 >= 0) v += ((f1 & 256) ? 0.5f : 1.f) * nf[a * NFEAT + (f1 & 255)];
        int f2 = g_fent[cj * 10 + ri];
        if (f2 >= 0) v += ((f2 & 256) ? 0.5f : 1.f) * nf[a * NFEAT + (f2 & 255)];
    }
    entval[(size_t)pos * 100 + elem] = v;
}

// B: streaming writer. Block (i, dk) writes rows [i*NO, +10) x NR for slab dk.
// Hot loop: one predicated entval load + fmul per element, coalesced float4 stores.
__global__ __launch_bounds__(256)
void b_write(const int* __restrict__ map, const int* __restrict__ paircnt,
             const int* __restrict__ pairoff, const int* __restrict__ entries,
             const float* __restrict__ entval, const float* __restrict__ coefE,
             float* __restrict__ out, int E, int N, int NK) {
    __shared__ int   sCNT[256];
    __shared__ int   sPOS[256];
    __shared__ float sCOEF[256];
    const int i  = blockIdx.x;
    const int dk = blockIdx.y;
    const int NR = N * NO;
    const int tid = threadIdx.x;
    const int E1 = E + 1;

    for (int j = tid; j < N; j += 256) {
        int pid = map[i * N + j];
        int cnt = 0, pos = 0; float cf = 0.f;
        if (pid >= 0) {
            cnt = paircnt[pid];
            pos = pairoff[pid];
            int ent = entries[pos];
            int e = (ent < 2 * E) ? (ent >> 1) : E;
            cf = coefE[dk * E1 + e];
        }
        sCNT[j] = cnt; sPOS[j] = pos; sCOEF[j] = cf;
    }
    __syncthreads();

    const int n4 = NR >> 2;
    size_t outbase = ((size_t)dk * NR + (size_t)i * NO) * NR;
    for (int c4 = tid; c4 < n4; c4 += 256) {
        int c = c4 * 4;
        int jj[4], cc[4];
#pragma unroll
        for (int t = 0; t < 4; ++t) {
            int ce = c + t; int jv = ce / 10;
            jj[t] = jv; cc[t] = ce - jv * 10;
        }
        for (int ri = 0; ri < NO; ++ri) {
            float v[4];
#pragma unroll
            for (int t = 0; t < 4; ++t) {
                int jv = jj[t];
                int cnt = sCNT[jv];
                float s = 0.f;
                if (cnt) {
                    int pos = sPOS[jv];
                    s = entval[(size_t)pos * 100 + ri * 10 + cc[t]] * sCOEF[jv];
                    for (int x = 1; x < cnt; ++x) {         // rare (multi-edge pairs)
                        int ent = entries[pos + x];
                        int e = (ent < 2 * E) ? (ent >> 1) : E;
                        s += entval[(size_t)(pos + x) * 100 + ri * 10 + cc[t]] * coefE[dk * E1 + e];
                    }
                }
                v[t] = s;
            }
            *(float4*)(out + outbase + (size_t)ri * NR + c) = make_float4(v[0], v[1], v[2], v[3]);
        }
    }
}

// ---------- fallback (round-7 kernel, 95 us) ----------
__global__ __launch_bounds__(512)
void fused1d(const float* __restrict__ ef, const float* __restrict__ nf,
             const float* __restrict__ ev, const float* __restrict__ ecs,
             const float* __restrict__ kp, const int* __restrict__ eidx,
             float* __restrict__ out,
             int E, int N, int NK, size_t lim) {
    __shared__ float acc[HR * MAXNR];
    __shared__ float coef[MAXLIST];
    __shared__ int   elist[MAXLIST];
    __shared__ int   mcnt;
    const int i = blockIdx.x, k = blockIdx.y;
    const int d = blockIdx.z >> 1, h = blockIdx.z & 1;
    const int r0 = h * HR;
    const int tid = threadIdx.x, nthr = blockDim.x;
    const int NR = N * NO;
    if (NR > MAXNR) return;
    if (tid == 0) mcnt = 0;
    __syncthreads();
    for (int e = tid; e < E; e += nthr) {
        int s = eidx[e], t = eidx[E + e];
        if (s == i) { int p = atomicAdd(&mcnt, 1); if (p < MAXLIST) elist[p] = e * 2; }
        if (t == i) { int p = atomicAdd(&mcnt, 1); if (p < MAXLIST) elist[p] = e * 2 + 1; }
    }
    {
        float4* a4 = (float4*)acc;
        int nz = (HR * NR) >> 2;
        float4 z = make_float4(0.f, 0.f, 0.f, 0.f);
        for (int x = tid; x < nz; x += nthr) a4[x] = z;
    }
    __syncthreads();
    const int m = min(mcnt, MAXLIST);
    const float k0v = kp[k*3], k1v = kp[k*3+1], k2v = kp[k*3+2];
    const float TWO_PI = 6.283185307179586f;
    for (int t = tid; t < m; t += nthr) {
        int e = elist[t] >> 1;
        float th = TWO_PI * (k0v*ecs[e*3] + k1v*ecs[e*3+1] + k2v*ecs[e*3+2]);
        coef[t] = -ev[e*3 + d] * sinf(th);
    }
    __syncthreads();
    const int items = m * NFEAT;
    for (int it = tid; it < items; it += nthr) {
        int t = it / NFEAT, f = it - t * NFEAT;
        int ent = elist[t], e = ent >> 1, dir = ent & 1;
        unsigned pk = g_pk[f];
        int oi = pk & 15, oj = (pk >> 4) & 15;
        int row = dir ? oj : oi, rr = row - r0;
        if ((unsigned)rr < HR) {
            int col = dir ? oi : oj;
            int j = dir ? eidx[e] : eidx[E + e];
            float fac = (pk & 256) ? 0.5f : 1.0f;
            atomicAdd(&acc[rr * NR + j * NO + col], coef[t] * fac * ef[e * NFEAT + f]);
        }
    }
    for (int f = tid; f < NFEAT; f += nthr) {
        unsigned pk = g_pk[f];
        int oi = pk & 15, oj = (pk >> 4) & 15;
        float v = ((pk & 256) ? 0.5f : 1.0f) * nf[i * NFEAT + f];
        int ra = oi - r0, rb = oj - r0;
        if ((unsigned)ra < HR) atomicAdd(&acc[ra * NR + i * NO + oj], v);
        if ((unsigned)rb < HR) atomicAdd(&acc[rb * NR + i * NO + oi], v);
    }
    __syncthreads();
    size_t base = ((size_t)(d * NK + k)) * NR * NR + (size_t)(i * NO + r0) * NR;
    int ntot = HR * NR;
    if ((NR & 3) == 0) {
        const float4* a4 = (const float4*)acc;
        int n4 = ntot >> 2;
        for (int x = tid; x < n4; x += nthr) {
            size_t idx = base + (size_t)x * 4;
            if (idx + 3 < lim) *(float4*)(out + idx) = a4[x];
        }
    } else {
        for (int x = tid; x < ntot; x += nthr) {
            size_t idx = base + x;
            if (idx < lim) out[idx] = acc[x];
        }
    }
}

extern "C" void kernel_launch(void* const* d_in, const int* in_sizes, int n_in,
                              void* d_out, int out_size, void* d_ws, size_t ws_size,
                              hipStream_t stream) {
    const float* ef  = (const float*)d_in[0];
    const float* nf  = (const float*)d_in[1];
    const float* ev  = (const float*)d_in[2];
    const float* ecs = (const float*)d_in[3];
    const float* kp  = (const float*)d_in[4];
    const int*  eidx = (const int*)d_in[5];
    float* out = (float*)d_out;

    int E  = in_sizes[0] / NFEAT;
    int N  = in_sizes[1] / NFEAT;
    int NK = in_sizes[4] / 3;
    int NR = N * NO;
    size_t lim = (size_t)out_size;       // 3*NK*NR*NR floats (real part)
    int total = 2 * E + N;               // CSR entries: 2 orientations + diagonals

    // workspace layout
    size_t o = 0;
    auto alloc = [&](size_t bytes) { size_t r = o; o = (o + bytes + 255) & ~(size_t)255; return r; };
    size_t o_hdr     = alloc(2 * 4);
    size_t o_coefE   = alloc((size_t)3 * NK * (E + 1) * 4);
    size_t o_map     = alloc((size_t)N * N * 4);
    size_t o_paircnt = alloc((size_t)MAXP * 4);
    size_t o_pairoff = alloc((size_t)MAXP * 4);
    size_t o_paircur = alloc((size_t)MAXP * 4);
    size_t o_entries = alloc((size_t)total * 4);
    size_t o_entval  = alloc((size_t)total * 100 * 4);
    size_t need = o;

    bool ok = (ws_size >= need) && ((NR & 3) == 0) && (N <= 256) &&
              (total <= MAXP) && (lim == (size_t)3 * NK * NR * NR);

    if (!ok) {
        dim3 grid(N, NK, 6);
        fused1d<<<grid, 512, 0, stream>>>(ef, nf, ev, ecs, kp, eidx, out, E, N, NK, lim);
        return;
    }

    char* ws = (char*)d_ws;
    int*   hdr     = (int*)(ws + o_hdr);
    float* coefE   = (float*)(ws + o_coefE);
    int*   map     = (int*)(ws + o_map);
    int*   paircnt = (int*)(ws + o_paircnt);
    int*   pairoff = (int*)(ws + o_pairoff);
    int*   paircur = (int*)(ws + o_paircur);
    int*   entries = (int*)(ws + o_entries);
    float* entval  = (float*)(ws + o_entval);

    int tb = (total + 255) / 256;
    g0_init<<<256, 256, 0, stream>>>(ecs, kp, ev, coefE, map, paircnt, hdr, E, N, NK);
    g1_claim<<<tb, 256, 0, stream>>>(eidx, map, hdr, E, N, total);
    g2_count<<<tb, 256, 0, stream>>>(eidx, map, paircnt, E, N, total);
    g3_off<<<MAXP / 256, 256, 0, stream>>>(paircnt, pairoff, paircur, hdr);
    g4_fill<<<tb, 256, 0, stream>>>(eidx, map, paircur, entries, E, N, total);
    a_build<<<(total * 100 + 255) / 256, 256, 0, stream>>>(ef, nf, entries, entval, E, total);

    dim3 gridB(N, 3 * NK);
    b_write<<<gridB, 256, 0, stream>>>(map, paircnt, pairoff, entries, entval, coefE,
                                       out, E, N, NK);
}

// Round 11
// 98.727 us; speedup vs baseline: 2.1897x; 1.3477x over previous
//
#include <hip/hip_runtime.h>
#include <math.h>

#define NO 10
#define NFEAT 68
#define HR 5
#define MAXNR 2048
#define MAXLIST 1024
#define MAXNA 256     // max atoms
#define CAP 8         // max entries per (i,j) pair (diag + multi-edges; overflow clamped)

// fent[oi*10+oj] = feature index | 256 (if fac==0.5), or -1 if below block-diagonal.
__device__ const int g_fent[100] = {
    256,  1,  2,  3,  4,  5,  6,  7,  8,  9,
     -1,266, 11, 12, 13, 14, 15, 16, 17, 18,
     -1, -1,275,276,277, 28, 29, 30, 31, 32,
     -1, -1,278,279,280, 33, 34, 35, 36, 37,
     -1, -1,281,282,283, 38, 39, 40, 41, 42,
     -1, -1, -1, -1, -1,299,300,301,302,303,
     -1, -1, -1, -1, -1,304,305,306,307,308,
     -1, -1, -1, -1, -1,309,310,311,312,313,
     -1, -1, -1, -1, -1,314,315,316,317,318,
     -1, -1, -1, -1, -1,319,320,321,322,323
};

// Packed feature table (fallback kernel): bits0-3=oi, 4-7=oj, bit8=(fac==0.5)
__device__ const unsigned short g_pk[NFEAT] = {
    0x100, 0x010, 0x020, 0x030, 0x040, 0x050, 0x060, 0x070, 0x080, 0x090,
    0x111, 0x021, 0x031, 0x041, 0x051, 0x061, 0x071, 0x081, 0x091,
    0x122, 0x132, 0x142, 0x123, 0x133, 0x143, 0x124, 0x134, 0x144,
    0x052, 0x062, 0x072, 0x082, 0x092,
    0x053, 0x063, 0x073, 0x083, 0x093,
    0x054, 0x064, 0x074, 0x084, 0x094,
    0x155, 0x165, 0x175, 0x185, 0x195,
    0x156, 0x166, 0x176, 0x186, 0x196,
    0x157, 0x167, 0x177, 0x187, 0x197,
    0x158, 0x168, 0x178, 0x188, 0x198,
    0x159, 0x169, 0x179, 0x189, 0x199
};

// work item idx: [0,E) edge fwd (a=src,b=dst); [E,2E) edge transposed; [2E,2E+N) diag atom.
__device__ __forceinline__ void decode_ab(const int* __restrict__ eidx, int E, int idx,
                                          int& a, int& b) {
    if (idx < E)          { a = eidx[idx];        b = eidx[E + idx]; }
    else if (idx < 2 * E) { int e = idx - E; a = eidx[E + e]; b = eidx[e]; }
    else                  { a = idx - 2 * E; b = a; }
}

// kA: all input-only precompute. coefE[dk*(E+1)+e] = -v_d*sin(2pi k.R_e) (sentinel e=E -> 1);
// cnt[N*N] = 0; entval[idx*100 + ri*10 + cj] = pre-reduced block values.
__global__ void kA(const float* __restrict__ ecs, const float* __restrict__ kp,
                   const float* __restrict__ ev, const float* __restrict__ ef,
                   const float* __restrict__ nf, float* __restrict__ coefE,
                   int* __restrict__ cnt, float* __restrict__ entval,
                   int E, int N, int NK, int total) {
    int idx0 = blockIdx.x * blockDim.x + threadIdx.x;
    int stride = gridDim.x * blockDim.x;
    const float TWO_PI = 6.283185307179586f;
    int E1 = E + 1;
    int NDK = 3 * NK;
    for (int x = idx0; x < NDK * E1; x += stride) {
        int dk = x / E1, e = x - dk * E1;
        float v;
        if (e == E) v = 1.0f;
        else {
            int d = dk / NK, k = dk - d * NK;
            float th = TWO_PI * (kp[k*3]*ecs[e*3] + kp[k*3+1]*ecs[e*3+1] + kp[k*3+2]*ecs[e*3+2]);
            v = -ev[e * 3 + d] * sinf(th);
        }
        coefE[x] = v;
    }
    for (int x = idx0; x < N * N; x += stride) cnt[x] = 0;
    for (int x = idx0; x < total * 100; x += stride) {
        int pos = x / 100, elem = x - pos * 100;
        int ri = elem / 10, cj = elem - ri * 10;
        float v = 0.f;
        if (pos < E) {                       // fwd edge block
            int fe = g_fent[ri * 10 + cj];
            if (fe >= 0) v = ((fe & 256) ? 0.5f : 1.f) * ef[pos * NFEAT + (fe & 255)];
        } else if (pos < 2 * E) {            // transposed edge block
            int e = pos - E;
            int fe = g_fent[cj * 10 + ri];
            if (fe >= 0) v = ((fe & 256) ? 0.5f : 1.f) * ef[e * NFEAT + (fe & 255)];
        } else {                             // diagonal atom: D + D^T
            int a = pos - 2 * E;
            int f1 = g_fent[ri * 10 + cj];
            if (f1 >= 0) v += ((f1 & 256) ? 0.5f : 1.f) * nf[a * NFEAT + (f1 & 255)];
            int f2 = g_fent[cj * 10 + ri];
            if (f2 >= 0) v += ((f2 & 256) ? 0.5f : 1.f) * nf[a * NFEAT + (f2 & 255)];
        }
        entval[x] = v;
    }
}

// kB: append each work item into its dense (a,b) slot list.
__global__ void kB(const int* __restrict__ eidx, int* __restrict__ cnt,
                   int* __restrict__ ents, int E, int N, int total) {
    int idx = blockIdx.x * blockDim.x + threadIdx.x;
    if (idx >= total) return;
    int a, b; decode_ab(eidx, E, idx, a, b);
    int p = a * N + b;
    int s = atomicAdd(&cnt[p], 1);
    if (s < CAP) ents[p * CAP + s] = idx;
}

// kW: streaming writer. Block (i, dk) writes rows [i*NO, +10) x NR for slab dk.
// All per-j lookup state staged in LDS; hot loop = LDS count + <=1 entval load + FMA + store.
__global__ __launch_bounds__(256)
void kW(const int* __restrict__ cnt, const int* __restrict__ ents,
        const float* __restrict__ entval, const float* __restrict__ coefE,
        float* __restrict__ out, int E, int N, int NK) {
    __shared__ int   sN[MAXNA];
    __shared__ int   sB[MAXNA * CAP];
    __shared__ float sC[MAXNA * CAP];
    const int i  = blockIdx.x;
    const int dk = blockIdx.y;
    const int NR = N * NO;
    const int tid = threadIdx.x;
    const int E1 = E + 1;
    const int twoE = 2 * E;

    for (int j = tid; j < N; j += 256) {
        int p = i * N + j;
        int m = min(cnt[p], CAP);
        sN[j] = m;
        for (int s = 0; s < m; ++s) {
            int ent = ents[p * CAP + s];
            int e = (ent < E) ? ent : ((ent < twoE) ? ent - E : E);
            sB[j * CAP + s] = ent * 100;
            sC[j * CAP + s] = coefE[dk * E1 + e];
        }
    }
    __syncthreads();

    const int n4 = NR >> 2;
    size_t outbase = ((size_t)dk * NR + (size_t)i * NO) * NR;
    for (int c4 = tid; c4 < n4; c4 += 256) {
        int c = c4 * 4;
        int jj[4], cc[4];
#pragma unroll
        for (int t = 0; t < 4; ++t) {
            int ce = c + t; int jv = ce / 10;
            jj[t] = jv; cc[t] = ce - jv * 10;
        }
        for (int ri = 0; ri < NO; ++ri) {
            int off = ri * 10;
            float v[4];
#pragma unroll
            for (int t = 0; t < 4; ++t) {
                int j = jj[t];
                int m = sN[j];
                float s = 0.f;
                if (m) {
                    int o = off + cc[t];
                    s = entval[sB[j * CAP] + o] * sC[j * CAP];
                    for (int x = 1; x < m; ++x)
                        s += entval[sB[j * CAP + x] + o] * sC[j * CAP + x];
                }
                v[t] = s;
            }
            *(float4*)(out + outbase + (size_t)ri * NR + c) = make_float4(v[0], v[1], v[2], v[3]);
        }
    }
}

// ---------- fallback (round-7 kernel, 95 us) ----------
__global__ __launch_bounds__(512)
void fused1d(const float* __restrict__ ef, const float* __restrict__ nf,
             const float* __restrict__ ev, const float* __restrict__ ecs,
             const float* __restrict__ kp, const int* __restrict__ eidx,
             float* __restrict__ out,
             int E, int N, int NK, size_t lim) {
    __shared__ float acc[HR * MAXNR];
    __shared__ float coef[MAXLIST];
    __shared__ int   elist[MAXLIST];
    __shared__ int   mcnt;
    const int i = blockIdx.x, k = blockIdx.y;
    const int d = blockIdx.z >> 1, h = blockIdx.z & 1;
    const int r0 = h * HR;
    const int tid = threadIdx.x, nthr = blockDim.x;
    const int NR = N * NO;
    if (NR > MAXNR) return;
    if (tid == 0) mcnt = 0;
    __syncthreads();
    for (int e = tid; e < E; e += nthr) {
        int s = eidx[e], t = eidx[E + e];
        if (s == i) { int p = atomicAdd(&mcnt, 1); if (p < MAXLIST) elist[p] = e * 2; }
        if (t == i) { int p = atomicAdd(&mcnt, 1); if (p < MAXLIST) elist[p] = e * 2 + 1; }
    }
    {
        float4* a4 = (float4*)acc;
        int nz = (HR * NR) >> 2;
        float4 z = make_float4(0.f, 0.f, 0.f, 0.f);
        for (int x = tid; x < nz; x += nthr) a4[x] = z;
    }
    __syncthreads();
    const int m = min(mcnt, MAXLIST);
    const float k0v = kp[k*3], k1v = kp[k*3+1], k2v = kp[k*3+2];
    const float TWO_PI = 6.283185307179586f;
    for (int t = tid; t < m; t += nthr) {
        int e = elist[t] >> 1;
        float th = TWO_PI * (k0v*ecs[e*3] + k1v*ecs[e*3+1] + k2v*ecs[e*3+2]);
        coef[t] = -ev[e*3 + d] * sinf(th);
    }
    __syncthreads();
    const int items = m * NFEAT;
    for (int it = tid; it < items; it += nthr) {
        int t = it / NFEAT, f = it - t * NFEAT;
        int ent = elist[t], e = ent >> 1, dir = ent & 1;
        unsigned pk = g_pk[f];
        int oi = pk & 15, oj = (pk >> 4) & 15;
        int row = dir ? oj : oi, rr = row - r0;
        if ((unsigned)rr < HR) {
            int col = dir ? oi : oj;
            int j = dir ? eidx[e] : eidx[E + e];
            float fac = (pk & 256) ? 0.5f : 1.0f;
            atomicAdd(&acc[rr * NR + j * NO + col], coef[t] * fac * ef[e * NFEAT + f]);
        }
    }
    for (int f = tid; f < NFEAT; f += nthr) {
        unsigned pk = g_pk[f];
        int oi = pk & 15, oj = (pk >> 4) & 15;
        float v = ((pk & 256) ? 0.5f : 1.0f) * nf[i * NFEAT + f];
        int ra = oi - r0, rb = oj - r0;
        if ((unsigned)ra < HR) atomicAdd(&acc[ra * NR + i * NO + oj], v);
        if ((unsigned)rb < HR) atomicAdd(&acc[rb * NR + i * NO + oi], v);
    }
    __syncthreads();
    size_t base = ((size_t)(d * NK + k)) * NR * NR + (size_t)(i * NO + r0) * NR;
    int ntot = HR * NR;
    if ((NR & 3) == 0) {
        const float4* a4 = (const float4*)acc;
        int n4 = ntot >> 2;
        for (int x = tid; x < n4; x += nthr) {
            size_t idx = base + (size_t)x * 4;
            if (idx + 3 < lim) *(float4*)(out + idx) = a4[x];
        }
    } else {
        for (int x = tid; x < ntot; x += nthr) {
            size_t idx = base + x;
            if (idx < lim) out[idx] = acc[x];
        }
    }
}

extern "C" void kernel_launch(void* const* d_in, const int* in_sizes, int n_in,
                              void* d_out, int out_size, void* d_ws, size_t ws_size,
                              hipStream_t stream) {
    const float* ef  = (const float*)d_in[0];
    const float* nf  = (const float*)d_in[1];
    const float* ev  = (const float*)d_in[2];
    const float* ecs = (const float*)d_in[3];
    const float* kp  = (const float*)d_in[4];
    const int*  eidx = (const int*)d_in[5];
    float* out = (float*)d_out;

    int E  = in_sizes[0] / NFEAT;
    int N  = in_sizes[1] / NFEAT;
    int NK = in_sizes[4] / 3;
    int NR = N * NO;
    size_t lim = (size_t)out_size;       // 3*NK*NR*NR floats (real part)
    int total = 2 * E + N;

    // workspace layout
    size_t o = 0;
    auto alloc = [&](size_t bytes) { size_t r = o; o = (o + bytes + 255) & ~(size_t)255; return r; };
    size_t o_coefE  = alloc((size_t)3 * NK * (E + 1) * 4);
    size_t o_cnt    = alloc((size_t)N * N * 4);
    size_t o_ents   = alloc((size_t)N * N * CAP * 4);
    size_t o_entval = alloc((size_t)total * 100 * 4);
    size_t need = o;

    bool ok = (ws_size >= need) && ((NR & 3) == 0) && (N <= MAXNA) &&
              (lim == (size_t)3 * NK * NR * NR);

    if (!ok) {
        dim3 grid(N, NK, 6);
        fused1d<<<grid, 512, 0, stream>>>(ef, nf, ev, ecs, kp, eidx, out, E, N, NK, lim);
        return;
    }

    char* ws = (char*)d_ws;
    float* coefE  = (float*)(ws + o_coefE);
    int*   cnt    = (int*)(ws + o_cnt);
    int*   ents   = (int*)(ws + o_ents);
    float* entval = (float*)(ws + o_entval);

    kA<<<1024, 256, 0, stream>>>(ecs, kp, ev, ef, nf, coefE, cnt, entval, E, N, NK, total);
    kB<<<(total + 255) / 256, 256, 0, stream>>>(eidx, cnt, ents, E, N, total);
    dim3 gridW(N, 3 * NK);
    kW<<<gridW, 256, 0, stream>>>(cnt, ents, entval, coefE, out, E, N, NK);
}